// Round 4
// baseline (10891.782 us; speedup 1.0000x reference)
//
#include <hip/hip_runtime.h>
#include <cstdint>

// HardLSTM: T=512 B=32 I=512 H=1024, 2 layers, bidirectional.
// cvt(fp32->fp16) -> GEMM gx0 -> persistent recur L0 -> GEMM gx1 -> recur L1.
// Recurrence: h exchanged via sc0|sc1 (coherent-at-L3) accesses, no fences.
// 32 WGs/dir x 32 units/WG. Handshake = per-dir monotonic atomic counter;
// all waves poll one address. Only lgkm-only barriers in the loop.

typedef _Float16 half8 __attribute__((ext_vector_type(8)));
typedef _Float16 half4v __attribute__((ext_vector_type(4)));
typedef float floatx4 __attribute__((ext_vector_type(4)));
typedef int int4v __attribute__((ext_vector_type(4)));

#define T_LEN 512
#define BATCH 32
#define HID 1024
#define NTB 16384   // T*B
#define UPW 32      // hidden units per WG
#define WPD 32      // WGs per direction

__device__ __forceinline__ float hsig(float x) {
  return fminf(fmaxf(fmaf(0.2f, x, 0.5f), 0.0f), 1.0f);
}
__device__ __forceinline__ float htanh(float x) {
  return fminf(fmaxf(x, -1.0f), 1.0f);
}

__device__ __forceinline__ int4v load_co16(const void* p) {
  int4v r;
  asm volatile("global_load_dwordx4 %0, %1, off sc0 sc1"
               : "=&v"(r) : "v"(p) : "memory");
  return r;
}
__device__ __forceinline__ void store_co16(void* p, int4v v) {
  asm volatile("global_store_dwordx4 %0, %1, off sc0 sc1"
               :: "v"(p), "v"(v) : "memory");
}
__device__ __forceinline__ void waitcnt0() {
  asm volatile("s_waitcnt vmcnt(0)" ::: "memory");
}
// barrier with LDS-visibility only (no vmcnt drain)
__device__ __forceinline__ void barrier_lgkm() {
  asm volatile("s_waitcnt lgkmcnt(0)" ::: "memory");
  __builtin_amdgcn_sched_barrier(0);
  __builtin_amdgcn_s_barrier();
  __builtin_amdgcn_sched_barrier(0);
}

__device__ __forceinline__ void gll16(const void* g, void* l) {
  __builtin_amdgcn_global_load_lds((const __attribute__((address_space(1))) void*)g,
                                   (__attribute__((address_space(3))) void*)l,
                                   16, 0, 0);
}

// 4x4 transpose across fk lane-groups: v[r] = (gate fk, unit r, batch fr)
// -> lane gets all 4 gates of unit fk. (proven in round 3)
__device__ __forceinline__ void gate_xpose(floatx4 v, bool i1, bool i0,
                                           float& gI, float& gF,
                                           float& gG, float& gO) {
  float s0 = i1 ? v[0] : v[2], s1 = i1 ? v[1] : v[3];
  float r0 = __shfl_xor(s0, 32), r1 = __shfl_xor(s1, 32);
  float A0 = i1 ? r0 : v[0], A1 = i1 ? r1 : v[1];
  float A2 = i1 ? v[2] : r0, A3 = i1 ? v[3] : r1;
  s0 = i0 ? A0 : A1; s1 = i0 ? A2 : A3;
  r0 = __shfl_xor(s0, 16); r1 = __shfl_xor(s1, 16);
  gI = i0 ? r0 : A0; gF = i0 ? A1 : r0;
  gG = i0 ? r1 : A2; gO = i0 ? A3 : r1;
}

__global__ __launch_bounds__(256) void cvt_f32_f16(const float* __restrict__ s,
                                                   _Float16* __restrict__ d,
                                                   int n4) {
  int i = blockIdx.x * blockDim.x + threadIdx.x;
  int stride = gridDim.x * blockDim.x;
  for (; i < n4; i += stride) {
    float4 v = ((const float4*)s)[i];
    half4v h = {(_Float16)v.x, (_Float16)v.y, (_Float16)v.z, (_Float16)v.w};
    ((half4v*)d)[i] = h;
  }
}

// C[M=8192][NTB] = A[M][K] * B[NTB][K]^T + bias[M], fp16 out. (unchanged)
__global__ __launch_bounds__(256) void gemm_gx(const _Float16* __restrict__ A,
                                               const _Float16* __restrict__ B,
                                               const float* __restrict__ bias,
                                               _Float16* __restrict__ C,
                                               int K) {
  __shared__ __align__(16) _Float16 A_s[128 * 64];
  __shared__ __align__(16) _Float16 B_s[128 * 64];
  const int tid = threadIdx.x;
  const int lane = tid & 63;
  const int w = tid >> 6;
  const int bm = blockIdx.x >> 7;
  const int bn = blockIdx.x & 127;
  const int m0 = bm * 128, n0 = bn * 128;

  floatx4 acc[4][4] = {};

  const int srow = w * 8 + (lane >> 3);
  const int scol = ((lane & 7) ^ ((lane >> 3) & 7)) * 8;
  const _Float16* Ag = A + (size_t)(m0 + srow) * K + scol;
  const _Float16* Bg = B + (size_t)(n0 + srow) * K + scol;
  char* As_base = (char*)A_s + (size_t)(w * 8) * 128;
  char* Bs_base = (char*)B_s + (size_t)(w * 8) * 128;

  const int wm = (w >> 1) * 64;
  const int wn = (w & 1) * 64;
  const int fr = lane & 15;
  const int fk = lane >> 4;

  for (int kb = 0; kb < K; kb += 64) {
#pragma unroll
    for (int i = 0; i < 4; ++i) {
      gll16(Ag + (size_t)i * 32 * K + kb, As_base + i * 32 * 128);
      gll16(Bg + (size_t)i * 32 * K + kb, Bs_base + i * 32 * 128);
    }
    __syncthreads();
#pragma unroll
    for (int kt = 0; kt < 2; ++kt) {
      half8 af[4], bf[4];
#pragma unroll
      for (int mi = 0; mi < 4; ++mi) {
        int row = wm + mi * 16 + fr;
        int k8 = kt * 4 + fk;
        af[mi] = *(const half8*)(A_s + row * 64 + ((k8 ^ (row & 7)) << 3));
      }
#pragma unroll
      for (int ni = 0; ni < 4; ++ni) {
        int row = wn + ni * 16 + fr;
        int k8 = kt * 4 + fk;
        bf[ni] = *(const half8*)(B_s + row * 64 + ((k8 ^ (row & 7)) << 3));
      }
#pragma unroll
      for (int mi = 0; mi < 4; ++mi)
#pragma unroll
        for (int ni = 0; ni < 4; ++ni)
          acc[mi][ni] = __builtin_amdgcn_mfma_f32_16x16x32_f16(af[mi], bf[ni],
                                                               acc[mi][ni], 0, 0, 0);
    }
    __syncthreads();
  }

#pragma unroll
  for (int mi = 0; mi < 4; ++mi) {
    int rowb = m0 + wm + mi * 16 + fk * 4;
#pragma unroll
    for (int r = 0; r < 4; ++r) {
      float bv = bias[rowb + r];
#pragma unroll
      for (int ni = 0; ni < 4; ++ni) {
        int col = n0 + wn + ni * 16 + fr;
        C[(size_t)(rowb + r) * NTB + col] = (_Float16)(acc[mi][ni][r] + bv);
      }
    }
  }
}

// Persistent bidirectional recurrence. Grid = 64 WGs x 512 thr.
// Wave w owns 16 gate rows = 4 gates x 4 units (units u0+w*4+du), both batch
// halves (2 N-tiles). Lane (fk,fr): A row fr -> gate fr>>2, du fr&3.
// Post-MFMA 4x4 lane-group transpose -> lane owns unit u0+w*4+fk, batches
// fr and 16+fr.
__global__ __launch_bounds__(512) void recur(const _Float16* __restrict__ gx,
                                             const _Float16* __restrict__ whh,
                                             const float* __restrict__ h0,
                                             const float* __restrict__ c0,
                                             _Float16* __restrict__ hbuf,
                                             int* __restrict__ cnt_base,
                                             int layer,
                                             _Float16* __restrict__ yf16,
                                             float* __restrict__ yf32,
                                             float* __restrict__ hn,
                                             float* __restrict__ cn) {
  __shared__ __align__(16) _Float16 h_s[BATCH * HID];      // 64KB swizzled [b][k]
  __shared__ __align__(16) _Float16 hout_s[BATCH * UPW];   // 2KB

  const int tid = threadIdx.x;
  const int lane = tid & 63;
  const int w = tid >> 6;
  const int dir = blockIdx.x >> 5;
  const int wgd = blockIdx.x & 31;
  const int u0 = wgd * UPW;
  const int fr = lane & 15, fk = lane >> 4;

  int* cnt = cnt_base + dir * 32;

  // A fragments: lane supplies row fr -> gate g=fr>>2, unit offset du=fr&3
  half8 af[32];
  {
    const int g = fr >> 2, du = fr & 3;
    const _Float16* wrow = whh + ((size_t)dir * 4096 + g * 1024 + u0 + w * 4 + du) * HID;
#pragma unroll
    for (int kt = 0; kt < 32; ++kt)
      af[kt] = *(const half8*)(wrow + kt * 32 + fk * 8);
  }

  const int unit = u0 + w * 4 + fk;    // this lane's unit (post-transpose)
  const int batA = fr, batB = 16 + fr; // this lane's two batches
  const size_t st0 = (size_t)(layer * 2 + dir) * (BATCH * HID);
  float cA = c0[st0 + (size_t)batA * HID + unit];
  float cB = c0[st0 + (size_t)batB * HID + unit];

  _Float16* buf0 = hbuf + (size_t)dir * (BATCH * HID);
  _Float16* buf1 = hbuf + (size_t)(2 + dir) * (BATCH * HID);

  // init: publish this WG's h0 slice into buf0, counter += 1
  hout_s[batA * UPW + w * 4 + fk] = (_Float16)h0[st0 + (size_t)batA * HID + unit];
  hout_s[batB * UPW + w * 4 + fk] = (_Float16)h0[st0 + (size_t)batB * HID + unit];
  __syncthreads();
  if (w == 0) {
#pragma unroll
    for (int j = 0; j < 2; ++j) {
      int idx = j * 64 + lane;            // 128 chunks of 16B
      int b = idx >> 2, part = idx & 3;
      int4v v = *(const int4v*)(hout_s + idx * 8);
      store_co16(buf0 + (size_t)b * HID + u0 + part * 8, v);
    }
    waitcnt0();
    if (lane == 0)
      __hip_atomic_fetch_add(cnt, 1, __ATOMIC_RELAXED, __HIP_MEMORY_SCOPE_AGENT);
  }

  const size_t GS = (size_t)1024 * NTB;
  const _Float16* gxp = gx + ((size_t)dir * 4096 + unit) * NTB;

  // preload gx for t=0
  int ts0 = dir ? (T_LEN - 1) : 0;
  float gxiA = (float)gxp[0 * GS + (size_t)ts0 * BATCH + batA];
  float gxfA = (float)gxp[1 * GS + (size_t)ts0 * BATCH + batA];
  float gxgA = (float)gxp[2 * GS + (size_t)ts0 * BATCH + batA];
  float gxoA = (float)gxp[3 * GS + (size_t)ts0 * BATCH + batA];
  float gxiB = (float)gxp[0 * GS + (size_t)ts0 * BATCH + batB];
  float gxfB = (float)gxp[1 * GS + (size_t)ts0 * BATCH + batB];
  float gxgB = (float)gxp[2 * GS + (size_t)ts0 * BATCH + batB];
  float gxoB = (float)gxp[3 * GS + (size_t)ts0 * BATCH + batB];

  const bool i1 = (fk >> 1) & 1, i0 = fk & 1;

  for (int t = 0; t < T_LEN; ++t) {
    // all waves poll one uniform counter address (one coalesced dword/wave)
    {
      const int target = WPD * (t + 1);
      for (;;) {
        int v;
        asm volatile("global_load_dword %0, %1, off sc0 sc1\n\ts_waitcnt vmcnt(0)"
                     : "=&v"(v) : "v"(cnt) : "memory");
        if (v >= target) break;
        __builtin_amdgcn_s_sleep(1);
      }
    }

    const _Float16* src = (t & 1) ? buf1 : buf0;
    _Float16* dst = (t & 1) ? buf0 : buf1;

    // stage h(t-1): coherent load -> regs -> swizzled LDS
    int4v hv[8];
#pragma unroll
    for (int i = 0; i < 8; ++i)
      hv[i] = load_co16((const char*)src + (size_t)(i * 512 + tid) * 16);
    waitcnt0();
#pragma unroll
    for (int i = 0; i < 8; ++i) {
      int cbyte = (i * 512 + tid) * 16;
      int b = cbyte >> 11;
      int slot = cbyte & 2047;
      *(int4v*)((char*)h_s + b * 2048 + (slot ^ ((b & 7) << 4))) = hv[i];
    }

    // prefetch gx(t+1): latency hides under MFMA + next poll
    int tn = (t + 1 < T_LEN) ? t + 1 : t;
    int tsn = dir ? (T_LEN - 1 - tn) : tn;
    float ngxiA = (float)gxp[0 * GS + (size_t)tsn * BATCH + batA];
    float ngxfA = (float)gxp[1 * GS + (size_t)tsn * BATCH + batA];
    float ngxgA = (float)gxp[2 * GS + (size_t)tsn * BATCH + batA];
    float ngxoA = (float)gxp[3 * GS + (size_t)tsn * BATCH + batA];
    float ngxiB = (float)gxp[0 * GS + (size_t)tsn * BATCH + batB];
    float ngxfB = (float)gxp[1 * GS + (size_t)tsn * BATCH + batB];
    float ngxgB = (float)gxp[2 * GS + (size_t)tsn * BATCH + batB];
    float ngxoB = (float)gxp[3 * GS + (size_t)tsn * BATCH + batB];

    barrier_lgkm();  // h_s ready (no vmcnt drain)

    // MFMA: 16 rows x (2 x 16 batch) x K=1024; 2 chains per batch-tile
    floatx4 aA0 = {0.f,0.f,0.f,0.f}, aA1 = {0.f,0.f,0.f,0.f};
    floatx4 aB0 = {0.f,0.f,0.f,0.f}, aB1 = {0.f,0.f,0.f,0.f};
    {
      const char* hpA = (const char*)h_s + batA * 2048;
      const char* hpB = (const char*)h_s + batB * 2048;
      const int bxA = (batA & 7) << 4;
      const int bxB = (batB & 7) << 4;
#pragma unroll
      for (int kt = 0; kt < 32; kt += 2) {
        half8 b0A = *(const half8*)(hpA + ((kt * 64 + fk * 16) ^ bxA));
        half8 b0B = *(const half8*)(hpB + ((kt * 64 + fk * 16) ^ bxB));
        half8 b1A = *(const half8*)(hpA + (((kt + 1) * 64 + fk * 16) ^ bxA));
        half8 b1B = *(const half8*)(hpB + (((kt + 1) * 64 + fk * 16) ^ bxB));
        aA0 = __builtin_amdgcn_mfma_f32_16x16x32_f16(af[kt], b0A, aA0, 0, 0, 0);
        aB0 = __builtin_amdgcn_mfma_f32_16x16x32_f16(af[kt], b0B, aB0, 0, 0, 0);
        aA1 = __builtin_amdgcn_mfma_f32_16x16x32_f16(af[kt + 1], b1A, aA1, 0, 0, 0);
        aB1 = __builtin_amdgcn_mfma_f32_16x16x32_f16(af[kt + 1], b1B, aB1, 0, 0, 0);
      }
    }
    floatx4 vA = aA0 + aA1, vB = aB0 + aB1;

    float gI, gF, gG, gO;
    gate_xpose(vA, i1, i0, gI, gF, gG, gO);
    float igA = hsig(gI + gxiA);
    float fgA = hsig(gF + gxfA);
    float ggA = htanh(gG + gxgA);
    float ogA = hsig(gO + gxoA);
    cA = fgA * cA + igA * ggA;
    float hA = ogA * htanh(cA);

    gate_xpose(vB, i1, i0, gI, gF, gG, gO);
    float igB = hsig(gI + gxiB);
    float fgB = hsig(gF + gxfB);
    float ggB = htanh(gG + gxgB);
    float ogB = hsig(gO + gxoB);
    cB = fgB * cB + igB * ggB;
    float hB = ogB * htanh(cB);

    hout_s[batA * UPW + w * 4 + fk] = (_Float16)hA;
    hout_s[batB * UPW + w * 4 + fk] = (_Float16)hB;

    const int tseq = dir ? (T_LEN - 1 - t) : t;
    size_t yA = ((size_t)tseq * BATCH + batA) * 2048 + (size_t)dir * 1024 + unit;
    size_t yB = ((size_t)tseq * BATCH + batB) * 2048 + (size_t)dir * 1024 + unit;
    if (yf16) { yf16[yA] = (_Float16)hA; yf16[yB] = (_Float16)hB; }
    else      { yf32[yA] = hA;           yf32[yB] = hB; }

    gxiA = ngxiA; gxfA = ngxfA; gxgA = ngxgA; gxoA = ngxoA;
    gxiB = ngxiB; gxfB = ngxfB; gxgB = ngxgB; gxoB = ngxoB;

    if (t == T_LEN - 1) {
      size_t oA = st0 + (size_t)batA * HID + unit;
      size_t oB = st0 + (size_t)batB * HID + unit;
      hn[oA] = hA; cn[oA] = cA;
      hn[oB] = hB; cn[oB] = cB;
    } else {
      barrier_lgkm();  // hout_s ready; all h_s reads of this step done
      if (w == 0) {
#pragma unroll
        for (int j = 0; j < 2; ++j) {
          int idx = j * 64 + lane;
          int b = idx >> 2, part = idx & 3;
          int4v vv = *(const int4v*)(hout_s + idx * 8);
          store_co16(dst + (size_t)b * HID + u0 + part * 8, vv);
        }
        waitcnt0();
        if (lane == 0)
          __hip_atomic_fetch_add(cnt, 1, __ATOMIC_RELAXED, __HIP_MEMORY_SCOPE_AGENT);
      }
      // non-wave0 waves run ahead into the next poll
    }
  }
}

extern "C" void kernel_launch(void* const* d_in, const int* in_sizes, int n_in,
                              void* d_out, int out_size, void* d_ws, size_t ws_size,
                              hipStream_t stream) {
  const float* x    = (const float*)d_in[0];
  const float* h0   = (const float*)d_in[1];
  const float* c0   = (const float*)d_in[2];
  const float* wih0 = (const float*)d_in[3];
  const float* whh0 = (const float*)d_in[4];
  const float* b0   = (const float*)d_in[5];
  const float* wih1 = (const float*)d_in[6];
  const float* whh1 = (const float*)d_in[7];
  const float* b1   = (const float*)d_in[8];
  float* out = (float*)d_out;

  char* ws = (char*)d_ws;
  size_t off = 0;
  int* flags = (int*)ws;                      off += 4096;
  _Float16* xh    = (_Float16*)(ws + off);    off += (size_t)8388608 * 2;
  _Float16* wih0h = (_Float16*)(ws + off);    off += (size_t)4194304 * 2;
  _Float16* whh0h = (_Float16*)(ws + off);    off += (size_t)8388608 * 2;
  _Float16* wih1h = (_Float16*)(ws + off);    off += (size_t)16777216 * 2;
  _Float16* whh1h = (_Float16*)(ws + off);    off += (size_t)8388608 * 2;
  _Float16* y0h   = (_Float16*)(ws + off);    off += (size_t)33554432 * 2;
  _Float16* hbuf  = (_Float16*)(ws + off);    off += (size_t)131072 * 2;
  _Float16* gxbuf = (_Float16*)(ws + off);    off += (size_t)134217728 * 2;

  hipMemsetAsync(flags, 0, 4096, stream);

  cvt_f32_f16<<<2048, 256, 0, stream>>>(x,    xh,    8388608 / 4);
  cvt_f32_f16<<<2048, 256, 0, stream>>>(wih0, wih0h, 4194304 / 4);
  cvt_f32_f16<<<2048, 256, 0, stream>>>(whh0, whh0h, 8388608 / 4);
  cvt_f32_f16<<<2048, 256, 0, stream>>>(wih1, wih1h, 16777216 / 4);
  cvt_f32_f16<<<2048, 256, 0, stream>>>(whh1, whh1h, 8388608 / 4);

  float* hn = out + 33554432;
  float* cn = out + 33685504;

  // layer 0
  gemm_gx<<<8192, 256, 0, stream>>>(wih0h, xh, b0, gxbuf, 512);
  recur<<<64, 512, 0, stream>>>(gxbuf, whh0h, h0, c0, hbuf, flags, 0,
                                y0h, nullptr, hn, cn);
  // layer 1
  gemm_gx<<<8192, 256, 0, stream>>>(wih1h, y0h, b1, gxbuf, 2048);
  recur<<<64, 512, 0, stream>>>(gxbuf, whh1h, h0, c0, hbuf, flags + 64, 1,
                                nullptr, out, hn, cn);
}

// Round 5
// 6393.435 us; speedup vs baseline: 1.7036x; 1.7036x over previous
//
#include <hip/hip_runtime.h>
#include <cstdint>

// HardLSTM: T=512 B=32 I=512 H=1024, 2 layers, bidirectional.
// cvt(fp32->fp16) -> GEMM gx0 -> persistent recur L0 -> GEMM gx1 -> recur L1.
// Recurrence: h exchanged via sc0|sc1 (coherent-at-L3) accesses, no fences.
// 64 WGs/dir x 16 units/WG. Handshake: per-WG flag array (parallel stores);
// wave0 polls all 64 flags (one lane each), other waves join at barrier.
// In-wave shfl gate transpose; lgkm-only barriers; gx prefetched 1 step ahead.

typedef _Float16 half8 __attribute__((ext_vector_type(8)));
typedef _Float16 half4v __attribute__((ext_vector_type(4)));
typedef float floatx4 __attribute__((ext_vector_type(4)));
typedef int int4v __attribute__((ext_vector_type(4)));

#define T_LEN 512
#define BATCH 32
#define HID 1024
#define NTB 16384   // T*B
#define UPW 16      // hidden units per WG
#define WPD 64      // WGs per direction

__device__ __forceinline__ float hsig(float x) {
  return fminf(fmaxf(fmaf(0.2f, x, 0.5f), 0.0f), 1.0f);
}
__device__ __forceinline__ float htanh(float x) {
  return fminf(fmaxf(x, -1.0f), 1.0f);
}

__device__ __forceinline__ int4v load_co16(const void* p) {
  int4v r;
  asm volatile("global_load_dwordx4 %0, %1, off sc0 sc1"
               : "=&v"(r) : "v"(p) : "memory");
  return r;
}
__device__ __forceinline__ void store_co16(void* p, int4v v) {
  asm volatile("global_store_dwordx4 %0, %1, off sc0 sc1"
               :: "v"(p), "v"(v) : "memory");
}
__device__ __forceinline__ void waitcnt0() {
  asm volatile("s_waitcnt vmcnt(0)" ::: "memory");
}
// barrier with LDS-visibility only (no vmcnt drain)
__device__ __forceinline__ void barrier_lgkm() {
  asm volatile("s_waitcnt lgkmcnt(0)" ::: "memory");
  __builtin_amdgcn_sched_barrier(0);
  __builtin_amdgcn_s_barrier();
  __builtin_amdgcn_sched_barrier(0);
}

__device__ __forceinline__ void gll16(const void* g, void* l) {
  __builtin_amdgcn_global_load_lds((const __attribute__((address_space(1))) void*)g,
                                   (__attribute__((address_space(3))) void*)l,
                                   16, 0, 0);
}

// 4x4 transpose across fk lane-groups: v[r] = (gate fk, unit r, batch fr)
// -> lane gets all 4 gates of unit fk. (proven r3)
__device__ __forceinline__ void gate_xpose(floatx4 v, bool i1, bool i0,
                                           float& gI, float& gF,
                                           float& gG, float& gO) {
  float s0 = i1 ? v[0] : v[2], s1 = i1 ? v[1] : v[3];
  float r0 = __shfl_xor(s0, 32), r1 = __shfl_xor(s1, 32);
  float A0 = i1 ? r0 : v[0], A1 = i1 ? r1 : v[1];
  float A2 = i1 ? v[2] : r0, A3 = i1 ? v[3] : r1;
  s0 = i0 ? A0 : A1; s1 = i0 ? A2 : A3;
  r0 = __shfl_xor(s0, 16); r1 = __shfl_xor(s1, 16);
  gI = i0 ? r0 : A0; gF = i0 ? A1 : r0;
  gG = i0 ? r1 : A2; gO = i0 ? A3 : r1;
}

__global__ __launch_bounds__(256) void cvt_f32_f16(const float* __restrict__ s,
                                                   _Float16* __restrict__ d,
                                                   int n4) {
  int i = blockIdx.x * blockDim.x + threadIdx.x;
  int stride = gridDim.x * blockDim.x;
  for (; i < n4; i += stride) {
    float4 v = ((const float4*)s)[i];
    half4v h = {(_Float16)v.x, (_Float16)v.y, (_Float16)v.z, (_Float16)v.w};
    ((half4v*)d)[i] = h;
  }
}

// C[M=8192][NTB] = A[M][K] * B[NTB][K]^T + bias[M], fp16 out. (unchanged)
__global__ __launch_bounds__(256) void gemm_gx(const _Float16* __restrict__ A,
                                               const _Float16* __restrict__ B,
                                               const float* __restrict__ bias,
                                               _Float16* __restrict__ C,
                                               int K) {
  __shared__ __align__(16) _Float16 A_s[128 * 64];
  __shared__ __align__(16) _Float16 B_s[128 * 64];
  const int tid = threadIdx.x;
  const int lane = tid & 63;
  const int w = tid >> 6;
  const int bm = blockIdx.x >> 7;
  const int bn = blockIdx.x & 127;
  const int m0 = bm * 128, n0 = bn * 128;

  floatx4 acc[4][4] = {};

  const int srow = w * 8 + (lane >> 3);
  const int scol = ((lane & 7) ^ ((lane >> 3) & 7)) * 8;
  const _Float16* Ag = A + (size_t)(m0 + srow) * K + scol;
  const _Float16* Bg = B + (size_t)(n0 + srow) * K + scol;
  char* As_base = (char*)A_s + (size_t)(w * 8) * 128;
  char* Bs_base = (char*)B_s + (size_t)(w * 8) * 128;

  const int wm = (w >> 1) * 64;
  const int wn = (w & 1) * 64;
  const int fr = lane & 15;
  const int fk = lane >> 4;

  for (int kb = 0; kb < K; kb += 64) {
#pragma unroll
    for (int i = 0; i < 4; ++i) {
      gll16(Ag + (size_t)i * 32 * K + kb, As_base + i * 32 * 128);
      gll16(Bg + (size_t)i * 32 * K + kb, Bs_base + i * 32 * 128);
    }
    __syncthreads();
#pragma unroll
    for (int kt = 0; kt < 2; ++kt) {
      half8 af[4], bf[4];
#pragma unroll
      for (int mi = 0; mi < 4; ++mi) {
        int row = wm + mi * 16 + fr;
        int k8 = kt * 4 + fk;
        af[mi] = *(const half8*)(A_s + row * 64 + ((k8 ^ (row & 7)) << 3));
      }
#pragma unroll
      for (int ni = 0; ni < 4; ++ni) {
        int row = wn + ni * 16 + fr;
        int k8 = kt * 4 + fk;
        bf[ni] = *(const half8*)(B_s + row * 64 + ((k8 ^ (row & 7)) << 3));
      }
#pragma unroll
      for (int mi = 0; mi < 4; ++mi)
#pragma unroll
        for (int ni = 0; ni < 4; ++ni)
          acc[mi][ni] = __builtin_amdgcn_mfma_f32_16x16x32_f16(af[mi], bf[ni],
                                                               acc[mi][ni], 0, 0, 0);
    }
    __syncthreads();
  }

#pragma unroll
  for (int mi = 0; mi < 4; ++mi) {
    int rowb = m0 + wm + mi * 16 + fk * 4;
#pragma unroll
    for (int r = 0; r < 4; ++r) {
      float bv = bias[rowb + r];
#pragma unroll
      for (int ni = 0; ni < 4; ++ni) {
        int col = n0 + wn + ni * 16 + fr;
        C[(size_t)(rowb + r) * NTB + col] = (_Float16)(acc[mi][ni][r] + bv);
      }
    }
  }
}

// Persistent bidirectional recurrence. Grid = 128 WGs x 512 thr.
// Wave w = (wu = w>>1, wn = w&1): A rows = 4 gates x 4 units (row = g*4+du,
// units u0 + wu*4 + du), batch half wn. Post-MFMA 4x4 lane-group transpose
// puts all 4 gates of unit (u0+wu*4+fk), batch (wn*16+fr) into one lane.
__global__ __launch_bounds__(512) void recur(const _Float16* __restrict__ gx,
                                             const _Float16* __restrict__ whh,
                                             const float* __restrict__ h0,
                                             const float* __restrict__ c0,
                                             _Float16* __restrict__ hbuf,
                                             int* __restrict__ flags,
                                             int layer,
                                             _Float16* __restrict__ yf16,
                                             float* __restrict__ yf32,
                                             float* __restrict__ hn,
                                             float* __restrict__ cn) {
  __shared__ __align__(16) _Float16 h_s[BATCH * HID];     // 64KB swizzled [b][k]
  __shared__ __align__(16) _Float16 hout_s[BATCH * UPW];  // 1KB

  const int tid = threadIdx.x;
  const int lane = tid & 63;
  const int w = tid >> 6;
  const int wu = w >> 1, wn = w & 1;
  const int dir = blockIdx.x >> 6;
  const int wgd = blockIdx.x & 63;
  const int u0 = wgd * UPW;
  const int fr = lane & 15, fk = lane >> 4;

  // A fragments: lane supplies row fr -> gate g=fr>>2, unit offset du=fr&3
  half8 af[32];
  {
    const int g = fr >> 2, du = fr & 3;
    const _Float16* wrow = whh + ((size_t)dir * 4096 + g * 1024 + u0 + wu * 4 + du) * HID;
#pragma unroll
    for (int kt = 0; kt < 32; ++kt)
      af[kt] = *(const half8*)(wrow + kt * 32 + fk * 8);
  }

  const int unit = u0 + wu * 4 + fk;   // this lane's unit (post-transpose)
  const int bat  = wn * 16 + fr;       // this lane's batch
  const size_t st0 = (size_t)(layer * 2 + dir) * (BATCH * HID);
  float c = c0[st0 + (size_t)bat * HID + unit];

  _Float16* buf0 = hbuf + (size_t)dir * (BATCH * HID);
  _Float16* buf1 = hbuf + (size_t)(2 + dir) * (BATCH * HID);
  int* fl = flags + dir * WPD;

  // init: publish this WG's h0 slice into buf0, flag=1
  hout_s[bat * UPW + wu * 4 + fk] = (_Float16)h0[st0 + (size_t)bat * HID + unit];
  __syncthreads();
  if (w == 0) {
    int b = lane >> 1, hf = lane & 1;
    int4v v = *(const int4v*)(hout_s + b * UPW + hf * 8);
    store_co16(buf0 + (size_t)b * HID + u0 + hf * 8, v);
    waitcnt0();
    if (lane == 0) {
      int fv = 1;
      asm volatile("global_store_dword %0, %1, off sc0 sc1"
                   :: "v"(fl + wgd), "v"(fv) : "memory");
    }
  }

  const size_t GS = (size_t)1024 * NTB;
  const _Float16* gxp = gx + ((size_t)dir * 4096 + unit) * NTB;

  // preload gx for t=0
  int ts0 = dir ? (T_LEN - 1) : 0;
  float gxi = (float)gxp[0 * GS + (size_t)ts0 * BATCH + bat];
  float gxf = (float)gxp[1 * GS + (size_t)ts0 * BATCH + bat];
  float gxg = (float)gxp[2 * GS + (size_t)ts0 * BATCH + bat];
  float gxo = (float)gxp[3 * GS + (size_t)ts0 * BATCH + bat];

  const bool i1 = (fk >> 1) & 1, i0 = fk & 1;

  for (int t = 0; t < T_LEN; ++t) {
    // wave0 polls the 64-flag array (one lane per flag); others join at barrier
    if (w == 0) {
      const int want = t + 1;
      for (;;) {
        int v;
        asm volatile("global_load_dword %0, %1, off sc0 sc1\n\ts_waitcnt vmcnt(0)"
                     : "=&v"(v) : "v"(fl + lane) : "memory");
        if (__all(v >= want)) break;
        __builtin_amdgcn_s_sleep(1);
      }
    }
    barrier_lgkm();  // release: all WGs of this dir have published h(t-1)

    const _Float16* src = (t & 1) ? buf1 : buf0;
    _Float16* dst = (t & 1) ? buf0 : buf1;

    // stage h(t-1): coherent load -> regs -> swizzled LDS
    int4v hv[8];
#pragma unroll
    for (int i = 0; i < 8; ++i)
      hv[i] = load_co16((const char*)src + (size_t)(i * 512 + tid) * 16);
    waitcnt0();
#pragma unroll
    for (int i = 0; i < 8; ++i) {
      int cbyte = (i * 512 + tid) * 16;
      int b = cbyte >> 11;
      int slot = cbyte & 2047;
      *(int4v*)((char*)h_s + b * 2048 + (slot ^ ((b & 7) << 4))) = hv[i];
    }

    // prefetch gx(t+1): latency hides under MFMA + next poll
    int tn = (t + 1 < T_LEN) ? t + 1 : t;
    int tsn = dir ? (T_LEN - 1 - tn) : tn;
    float ngxi = (float)gxp[0 * GS + (size_t)tsn * BATCH + bat];
    float ngxf = (float)gxp[1 * GS + (size_t)tsn * BATCH + bat];
    float ngxg = (float)gxp[2 * GS + (size_t)tsn * BATCH + bat];
    float ngxo = (float)gxp[3 * GS + (size_t)tsn * BATCH + bat];

    barrier_lgkm();  // h_s ready (no vmcnt drain)

    // MFMA: 16 rows (4 gates x 4 units) x 16 batch x K=1024, two chains
    floatx4 acc0 = {0.f, 0.f, 0.f, 0.f}, acc1 = {0.f, 0.f, 0.f, 0.f};
    {
      const char* hp = (const char*)h_s + bat * 2048;
      const int bx = (bat & 7) << 4;
#pragma unroll
      for (int kt = 0; kt < 32; kt += 2) {
        half8 b0 = *(const half8*)(hp + ((kt * 64 + fk * 16) ^ bx));
        half8 b1 = *(const half8*)(hp + (((kt + 1) * 64 + fk * 16) ^ bx));
        acc0 = __builtin_amdgcn_mfma_f32_16x16x32_f16(af[kt], b0, acc0, 0, 0, 0);
        acc1 = __builtin_amdgcn_mfma_f32_16x16x32_f16(af[kt + 1], b1, acc1, 0, 0, 0);
      }
    }
    floatx4 v = acc0 + acc1;

    float gI, gF, gG, gO;
    gate_xpose(v, i1, i0, gI, gF, gG, gO);

    float ig = hsig(gI + gxi);
    float fg = hsig(gF + gxf);
    float gg = htanh(gG + gxg);
    float og = hsig(gO + gxo);
    c = fg * c + ig * gg;
    float h = og * htanh(c);

    hout_s[bat * UPW + wu * 4 + fk] = (_Float16)h;

    const int tseq = dir ? (T_LEN - 1 - t) : t;
    size_t yidx = ((size_t)tseq * BATCH + bat) * 2048 + (size_t)dir * 1024 + unit;
    if (yf16) yf16[yidx] = (_Float16)h;
    else      yf32[yidx] = h;

    gxi = ngxi; gxf = ngxf; gxg = ngxg; gxo = ngxo;

    if (t == T_LEN - 1) {
      size_t o = st0 + (size_t)bat * HID + unit;
      hn[o] = h;
      cn[o] = c;
    } else {
      barrier_lgkm();  // hout_s ready; all h_s reads of this step done
      if (w == 0) {
        int b = lane >> 1, hf = lane & 1;
        int4v vv = *(const int4v*)(hout_s + b * UPW + hf * 8);
        store_co16(dst + (size_t)b * HID + u0 + hf * 8, vv);
        waitcnt0();
        if (lane == 0) {
          int fv = t + 2;
          asm volatile("global_store_dword %0, %1, off sc0 sc1"
                       :: "v"(fl + wgd), "v"(fv) : "memory");
        }
      }
      // non-wave0 waves run ahead to the next top barrier
    }
  }
}

extern "C" void kernel_launch(void* const* d_in, const int* in_sizes, int n_in,
                              void* d_out, int out_size, void* d_ws, size_t ws_size,
                              hipStream_t stream) {
  const float* x    = (const float*)d_in[0];
  const float* h0   = (const float*)d_in[1];
  const float* c0   = (const float*)d_in[2];
  const float* wih0 = (const float*)d_in[3];
  const float* whh0 = (const float*)d_in[4];
  const float* b0   = (const float*)d_in[5];
  const float* wih1 = (const float*)d_in[6];
  const float* whh1 = (const float*)d_in[7];
  const float* b1   = (const float*)d_in[8];
  float* out = (float*)d_out;

  char* ws = (char*)d_ws;
  size_t off = 0;
  int* flags = (int*)ws;                      off += 4096;
  _Float16* xh    = (_Float16*)(ws + off);    off += (size_t)8388608 * 2;
  _Float16* wih0h = (_Float16*)(ws + off);    off += (size_t)4194304 * 2;
  _Float16* whh0h = (_Float16*)(ws + off);    off += (size_t)8388608 * 2;
  _Float16* wih1h = (_Float16*)(ws + off);    off += (size_t)16777216 * 2;
  _Float16* whh1h = (_Float16*)(ws + off);    off += (size_t)8388608 * 2;
  _Float16* y0h   = (_Float16*)(ws + off);    off += (size_t)33554432 * 2;
  _Float16* hbuf  = (_Float16*)(ws + off);    off += (size_t)131072 * 2;
  _Float16* gxbuf = (_Float16*)(ws + off);    off += (size_t)134217728 * 2;

  hipMemsetAsync(flags, 0, 4096, stream);

  cvt_f32_f16<<<2048, 256, 0, stream>>>(x,    xh,    8388608 / 4);
  cvt_f32_f16<<<2048, 256, 0, stream>>>(wih0, wih0h, 4194304 / 4);
  cvt_f32_f16<<<2048, 256, 0, stream>>>(whh0, whh0h, 8388608 / 4);
  cvt_f32_f16<<<2048, 256, 0, stream>>>(wih1, wih1h, 16777216 / 4);
  cvt_f32_f16<<<2048, 256, 0, stream>>>(whh1, whh1h, 8388608 / 4);

  float* hn = out + 33554432;
  float* cn = out + 33685504;

  // layer 0
  gemm_gx<<<8192, 256, 0, stream>>>(wih0h, xh, b0, gxbuf, 512);
  recur<<<128, 512, 0, stream>>>(gxbuf, whh0h, h0, c0, hbuf, flags, 0,
                                 y0h, nullptr, hn, cn);
  // layer 1
  gemm_gx<<<8192, 256, 0, stream>>>(wih1h, y0h, b1, gxbuf, 2048);
  recur<<<128, 512, 0, stream>>>(gxbuf, whh1h, h0, c0, hbuf, flags + 128, 1,
                                 nullptr, out, hn, cn);
}